// Round 6
// baseline (412.224 us; speedup 1.0000x reference)
//
#include <hip/hip_runtime.h>
#include <hip/hip_bf16.h>
#include <math.h>

typedef __bf16 bf16;
typedef __bf16 bf16x4v __attribute__((ext_vector_type(4)));
typedef __bf16 bf16x8 __attribute__((ext_vector_type(8)));
typedef float  f32x4  __attribute__((ext_vector_type(4)));

#define HIDDEN 1024
#define TOKENS 4096   // B*S = 2*2048
#define FFDIM  4096
#define SEQ    2048
#define NHEAD  16

#define LOG2E 1.44269504088896340736f

// async 16B global -> LDS (lane i lands at ldsbase + 16*i)
__device__ __forceinline__ void async_copy16(bf16* lds, const bf16* g)
{
    __builtin_amdgcn_global_load_lds(
        (__attribute__((address_space(1))) void*)g,
        (__attribute__((address_space(3))) void*)lds,
        16, 0, 0);
}

// ---------------- fp32 -> bf16 weight conversion ----------------
__global__ __launch_bounds__(256) void cvt_kernel(const float* __restrict__ in,
                                                  bf16* __restrict__ out, int n)
{
    int i = (blockIdx.x * 256 + threadIdx.x) * 4;
    if (i >= n) return;
    float4 v = *(const float4*)&in[i];
    bf16x4v o = { (bf16)v.x, (bf16)v.y, (bf16)v.z, (bf16)v.w };
    *(bf16x4v*)&out[i] = o;
}

// 4x 1M-element tensors -> contiguous bf16 (Wq|Wk|Wv|Wo)
__global__ __launch_bounds__(256) void cvt4_kernel(const float* __restrict__ s0,
    const float* __restrict__ s1, const float* __restrict__ s2, const float* __restrict__ s3,
    bf16* __restrict__ out)
{
    const int M1 = 1 << 20;
    int i = (blockIdx.x * 256 + threadIdx.x) * 4;
    int sel = i >> 20;
    const float* src = (sel == 0) ? s0 : (sel == 1) ? s1 : (sel == 2) ? s2 : s3;
    float4 v = *(const float4*)&src[i & (M1 - 1)];
    bf16x4v o = { (bf16)v.x, (bf16)v.y, (bf16)v.z, (bf16)v.w };
    *(bf16x4v*)&out[i] = o;
}

__global__ __launch_bounds__(256) void concat_bias_kernel(const float* __restrict__ bq,
    const float* __restrict__ bk, const float* __restrict__ bv, float* __restrict__ o)
{
    int i = blockIdx.x * 256 + threadIdx.x;   // 0..3071
    float v = (i < 1024) ? bq[i] : (i < 2048 ? bk[i - 1024] : bv[i - 2048]);
    o[i] = v;
}

// ---------------- LayerNorm: fp32 in -> bf16 out, one block per row ----------------
__global__ __launch_bounds__(256) void ln_kernel(const float* __restrict__ in,
    const float* __restrict__ g, const float* __restrict__ be, bf16* __restrict__ out)
{
    int row = blockIdx.x;
    int tid = threadIdx.x;
    const float* x = in + (size_t)row * HIDDEN;
    int i0 = tid * 4;
    float4 v = *(const float4*)&x[i0];
    float s  = v.x + v.y + v.z + v.w;
    float s2 = v.x*v.x + v.y*v.y + v.z*v.z + v.w*v.w;
    #pragma unroll
    for (int off = 32; off > 0; off >>= 1) { s += __shfl_xor(s, off); s2 += __shfl_xor(s2, off); }
    __shared__ float red[2][4];
    int wave = tid >> 6;
    if ((tid & 63) == 0) { red[0][wave] = s; red[1][wave] = s2; }
    __syncthreads();
    float ts  = red[0][0] + red[0][1] + red[0][2] + red[0][3];
    float ts2 = red[1][0] + red[1][1] + red[1][2] + red[1][3];
    float mu   = ts  * (1.0f / HIDDEN);
    float var  = ts2 * (1.0f / HIDDEN) - mu * mu;
    float rstd = rsqrtf(var + 1e-5f);
    float4 gg = *(const float4*)&g[i0];
    float4 bb = *(const float4*)&be[i0];
    bf16x4v o;
    o[0] = (bf16)((v.x - mu) * rstd * gg.x + bb.x);
    o[1] = (bf16)((v.y - mu) * rstd * gg.y + bb.y);
    o[2] = (bf16)((v.z - mu) * rstd * gg.z + bb.z);
    o[3] = (bf16)((v.w - mu) * rstd * gg.w + bb.w);
    *(bf16x4v*)&out[(size_t)row * HIDDEN + i0] = o;
}

// ---------------- GEMM: C[M,N] = A[M,K] @ Bt[N,K]^T + bias ----------------
// BM=64, BN=128, BK=64; ping-pong LDS dbuf, prefetch-after-barrier (1 barrier/tile).
// EPI: 0 = bias, 1 = bias+GELU, 2 = bias+fp32 residual.
template<int EPI, typename OT>
__global__ __launch_bounds__(256) void gemm_bt(const bf16* __restrict__ A, const bf16* __restrict__ Bt,
    const float* __restrict__ bias, const float* __restrict__ res, OT* __restrict__ C,
    int M, int N, int K)
{
    __shared__ bf16 As[2][64 * 64];
    __shared__ bf16 Bs[2][128 * 64];
    int tid  = threadIdx.x;
    int wave = tid >> 6, lane = tid & 63;
    int lm = lane & 15, quad = lane >> 4;
    int m0 = blockIdx.x * 64, n0 = blockIdx.y * 128;
    int wm = (wave >> 1) * 32, wn = (wave & 1) * 64;
    int r8 = lane >> 3, c8 = lane & 7;          // staging: 8 rows x 128B per copy
    int gsw = (c8 ^ (r8 & 7)) * 8;              // swizzled source column (elems)
    const bf16* Ab = A  + (size_t)(m0 + r8) * K + gsw;
    const bf16* Bb = Bt + (size_t)(n0 + r8) * K + gsw;
    int ntiles = K >> 6;
    auto stage = [&](int buf, int k0) {
        #pragma unroll
        for (int ch = wave; ch < 8; ch += 4)
            async_copy16(&As[buf][ch * 512], Ab + (size_t)(ch * 8) * K + k0);
        #pragma unroll
        for (int ch = wave; ch < 16; ch += 4)
            async_copy16(&Bs[buf][ch * 512], Bb + (size_t)(ch * 8) * K + k0);
    };
    stage(0, 0);
    f32x4 acc[2][4] = {};
    for (int t = 0; t < ntiles; t++) {
        __syncthreads();                        // drains copies for tile t
        if (t + 1 < ntiles) stage((t + 1) & 1, (t + 1) << 6);   // overlaps compute t
        const bf16* as = As[t & 1];
        const bf16* bs = Bs[t & 1];
        bf16x8 af[2][2], bfr[4][2];
        #pragma unroll
        for (int ks = 0; ks < 2; ks++) {
            int co = ((ks * 4 + quad) ^ (lm & 7)) * 8;
            #pragma unroll
            for (int u = 0; u < 2; u++) af[u][ks]  = *(const bf16x8*)&as[(wm + u * 16 + lm) * 64 + co];
            #pragma unroll
            for (int u = 0; u < 4; u++) bfr[u][ks] = *(const bf16x8*)&bs[(wn + u * 16 + lm) * 64 + co];
        }
        #pragma unroll
        for (int mt = 0; mt < 2; mt++)
            #pragma unroll
            for (int nt = 0; nt < 4; nt++)
                #pragma unroll
                for (int ks = 0; ks < 2; ks++)
                    acc[mt][nt] = __builtin_amdgcn_mfma_f32_16x16x32_bf16(af[mt][ks], bfr[nt][ks], acc[mt][nt], 0, 0, 0);
    }
    #pragma unroll
    for (int mt = 0; mt < 2; mt++) {
        #pragma unroll
        for (int nt = 0; nt < 4; nt++) {
            int col = n0 + wn + nt * 16 + lm;
            float bv = bias[col];
            #pragma unroll
            for (int r = 0; r < 4; r++) {
                int row = m0 + wm + mt * 16 + quad * 4 + r;
                float vv = acc[mt][nt][r] + bv;
                if (EPI == 1) vv = 0.5f * vv * (1.0f + erff(vv * 0.70710678118654752f));
                if (EPI == 2) vv += res[(size_t)row * N + col];
                C[(size_t)row * N + col] = (OT)vv;
            }
        }
    }
}

// ---------------- fused QKV GEMM: BM=64 dbuf; V written transposed [b,h,d,s] ------
__global__ __launch_bounds__(256) void gemm_qkv(const bf16* __restrict__ A, const bf16* __restrict__ W,
    const float* __restrict__ bias, bf16* __restrict__ qb, bf16* __restrict__ kb, bf16* __restrict__ vt)
{
    constexpr int K = HIDDEN;
    constexpr int N = 3072;
    __shared__ bf16 As[2][64 * 64];
    __shared__ bf16 Bs[2][128 * 64];
    int tid  = threadIdx.x;
    int wave = tid >> 6, lane = tid & 63;
    int lm = lane & 15, quad = lane >> 4;
    int m0 = blockIdx.x * 64, n0 = blockIdx.y * 128;
    int wm = (wave >> 1) * 32, wn = (wave & 1) * 64;
    int r8 = lane >> 3, c8 = lane & 7;
    int gsw = (c8 ^ (r8 & 7)) * 8;
    const bf16* Ab = A + (size_t)(m0 + r8) * K + gsw;
    const bf16* Bb = W + (size_t)(n0 + r8) * K + gsw;
    auto stage = [&](int buf, int k0) {
        #pragma unroll
        for (int ch = wave; ch < 8; ch += 4)
            async_copy16(&As[buf][ch * 512], Ab + (size_t)(ch * 8) * K + k0);
        #pragma unroll
        for (int ch = wave; ch < 16; ch += 4)
            async_copy16(&Bs[buf][ch * 512], Bb + (size_t)(ch * 8) * K + k0);
    };
    stage(0, 0);
    f32x4 acc[2][4] = {};
    for (int t = 0; t < K / 64; t++) {
        __syncthreads();
        if (t + 1 < K / 64) stage((t + 1) & 1, (t + 1) << 6);
        const bf16* as = As[t & 1];
        const bf16* bs = Bs[t & 1];
        bf16x8 af[2][2], bfr[4][2];
        #pragma unroll
        for (int ks = 0; ks < 2; ks++) {
            int co = ((ks * 4 + quad) ^ (lm & 7)) * 8;
            #pragma unroll
            for (int u = 0; u < 2; u++) af[u][ks]  = *(const bf16x8*)&as[(wm + u * 16 + lm) * 64 + co];
            #pragma unroll
            for (int u = 0; u < 4; u++) bfr[u][ks] = *(const bf16x8*)&bs[(wn + u * 16 + lm) * 64 + co];
        }
        #pragma unroll
        for (int mt = 0; mt < 2; mt++)
            #pragma unroll
            for (int nt = 0; nt < 4; nt++)
                #pragma unroll
                for (int ks = 0; ks < 2; ks++)
                    acc[mt][nt] = __builtin_amdgcn_mfma_f32_16x16x32_bf16(af[mt][ks], bfr[nt][ks], acc[mt][nt], 0, 0, 0);
    }
    int region = n0 >> 10;    // 0:Q 1:K 2:V  (block-uniform; 1024 % 128 == 0)
    #pragma unroll
    for (int mt = 0; mt < 2; mt++) {
        #pragma unroll
        for (int nt = 0; nt < 4; nt++) {
            int col = n0 + wn + nt * 16 + lm;
            float bv = bias[col];
            int cl = col & 1023;
            #pragma unroll
            for (int r = 0; r < 4; r++) {
                int row = m0 + wm + mt * 16 + quad * 4 + r;
                float vv = acc[mt][nt][r] + bv;
                if (region == 0)      qb[(size_t)row * HIDDEN + cl] = (bf16)vv;
                else if (region == 1) kb[(size_t)row * HIDDEN + cl] = (bf16)vv;
                else {
                    int h = cl >> 6, d = cl & 63;
                    int b = row >> 11, s = row & 2047;
                    vt[(((size_t)(b * NHEAD + h)) * 64 + d) * SEQ + s] = (bf16)vv;
                }
            }
        }
    }
    (void)N;
}

// ---------------- Flash attention: dbuf staging + MFMA row-sums ---------------
__global__ __launch_bounds__(256) void attn_kernel(const bf16* __restrict__ Q, const bf16* __restrict__ K,
    const bf16* __restrict__ Vt, const float* __restrict__ mask, bf16* __restrict__ O)
{
    __shared__ bf16 Ks[2][64 * 64];     // [krow][d], 16B-chunk swizzled
    __shared__ bf16 Vs[2][64 * 64];     // [d][s],    16B-chunk swizzled
    __shared__ bf16 Ps[4][16 * 72];     // per-wave P [q][k], row stride 72
    int tid = threadIdx.x, wave = tid >> 6, lane = tid & 63;
    int lm = lane & 15, quad = lane >> 4;
    int bh = blockIdx.y, b = bh >> 4, h = bh & 15;
    int q0 = blockIdx.x * 64 + wave * 16;
    const size_t base  = ((size_t)b * SEQ) * HIDDEN + h * 64;   // Q/K token-major
    const size_t vbase = (size_t)bh * 64 * SEQ;                 // Vt [bh][d][s]
    int srow8 = lane >> 3, spos = lane & 7;
    bf16x8 qf[2];
    #pragma unroll
    for (int ks = 0; ks < 2; ks++)
        qf[ks] = *(const bf16x8*)&Q[base + (size_t)(q0 + lm) * HIDDEN + ks * 32 + quad * 8];
    bf16x8 onesf;
    #pragma unroll
    for (int i = 0; i < 8; i++) onesf[i] = (bf16)1.0f;
    f32x4 o[4] = {};
    f32x4 lacc = {};                               // row-sums via MFMA vs ones
    const float c0 = 0.125f * LOG2E;               // score scale, log2 domain
    const float cmk = 10000.0f * LOG2E;            // mask scale, log2 domain
    const float coff = -(cmk + 16.0f);             // folds (mv-1)*cmk - SHIFT
    bf16* pw = &Ps[wave][0];
    auto stage = [&](int buf, int kt) {
        #pragma unroll
        for (int ch = wave; ch < 8; ch += 4) {
            int r = ch * 8 + srow8;
            int gc = spos ^ (r & 7);
            async_copy16(&Ks[buf][ch * 512], &K [base  + (size_t)(kt + r) * HIDDEN + gc * 8]);
            async_copy16(&Vs[buf][ch * 512], &Vt[vbase + (size_t)r * SEQ + kt + gc * 8]);
        }
    };
    stage(0, 0);
    for (int ti = 0; ti < SEQ / 64; ti++) {
        __syncthreads();                           // copies for tile ti visible
        if (ti + 1 < SEQ / 64) stage((ti + 1) & 1, (ti + 1) * 64);
        const bf16* ksb = Ks[ti & 1];
        const bf16* vsb = Vs[ti & 1];
        int kt = ti * 64;
        // S^T: rows = k (reg dim), cols = q (lm)
        f32x4 st[4] = {};
        #pragma unroll
        for (int nt = 0; nt < 4; nt++) {
            #pragma unroll
            for (int ks = 0; ks < 2; ks++) {
                bf16x8 kf = *(const bf16x8*)&ksb[(nt * 16 + lm) * 64 + (((ks * 4 + quad) ^ (lm & 7)) * 8)];
                st[nt] = __builtin_amdgcn_mfma_f32_16x16x32_bf16(kf, qf[ks], st[nt], 0, 0, 0);
            }
        }
        // p = exp2(s*c0 + mv*cmk + coff); pack straight to P (per-wave LDS region)
        #pragma unroll
        for (int nt = 0; nt < 4; nt++) {
            float4 mv = *(const float4*)&mask[b * SEQ + kt + nt * 16 + quad * 4];
            float p0 = __builtin_amdgcn_exp2f(st[nt][0] * c0 + (mv.x * cmk + coff));
            float p1 = __builtin_amdgcn_exp2f(st[nt][1] * c0 + (mv.y * cmk + coff));
            float p2 = __builtin_amdgcn_exp2f(st[nt][2] * c0 + (mv.z * cmk + coff));
            float p3 = __builtin_amdgcn_exp2f(st[nt][3] * c0 + (mv.w * cmk + coff));
            bf16x4v pk = { (bf16)p0, (bf16)p1, (bf16)p2, (bf16)p3 };
            *(bf16x4v*)&pw[lm * 72 + nt * 16 + quad * 4] = pk;
        }
        // O += P @ V ; lacc += P @ ones (row-sums, already in C-layout for epilogue)
        bf16x8 pf[2];
        #pragma unroll
        for (int ks = 0; ks < 2; ks++)
            pf[ks] = *(const bf16x8*)&pw[lm * 72 + ks * 32 + quad * 8];
        lacc = __builtin_amdgcn_mfma_f32_16x16x32_bf16(pf[0], onesf, lacc, 0, 0, 0);
        lacc = __builtin_amdgcn_mfma_f32_16x16x32_bf16(pf[1], onesf, lacc, 0, 0, 0);
        #pragma unroll
        for (int dt = 0; dt < 4; dt++) {
            #pragma unroll
            for (int ks = 0; ks < 2; ks++) {
                bf16x8 vf = *(const bf16x8*)&vsb[(dt * 16 + lm) * 64 + (((ks * 4 + quad) ^ (lm & 7)) * 8)];
                o[dt] = __builtin_amdgcn_mfma_f32_16x16x32_bf16(pf[ks], vf, o[dt], 0, 0, 0);
            }
        }
    }
    #pragma unroll
    for (int r = 0; r < 4; r++) {
        float inv = 1.0f / lacc[r];                // sum for q-row quad*4+r (all cols equal)
        #pragma unroll
        for (int dt = 0; dt < 4; dt++) {
            float val = o[dt][r] * inv;
            O[base + (size_t)(q0 + quad * 4 + r) * HIDDEN + dt * 16 + lm] = (bf16)val;
        }
    }
}

extern "C" void kernel_launch(void* const* d_in, const int* in_sizes, int n_in,
                              void* d_out, int out_size, void* d_ws, size_t ws_size,
                              hipStream_t stream)
{
    (void)in_sizes; (void)n_in; (void)out_size; (void)ws_size;
    const float* x    = (const float*)d_in[0];
    const float* mask = (const float*)d_in[1];
    const float* Wq   = (const float*)d_in[2];
    const float* bq   = (const float*)d_in[3];
    const float* Wk   = (const float*)d_in[4];
    const float* bk   = (const float*)d_in[5];
    const float* Wv   = (const float*)d_in[6];
    const float* bv   = (const float*)d_in[7];
    const float* Wo   = (const float*)d_in[8];
    const float* bo   = (const float*)d_in[9];
    const float* W1   = (const float*)d_in[10];
    const float* b1   = (const float*)d_in[11];
    const float* W2   = (const float*)d_in[12];
    const float* b2   = (const float*)d_in[13];
    const float* g1   = (const float*)d_in[14];
    const float* be1  = (const float*)d_in[15];
    const float* g2   = (const float*)d_in[16];
    const float* be2  = (const float*)d_in[17];
    float* out = (float*)d_out;

    const size_t M1 = 1024u * 1024u;
    bf16* ws    = (bf16*)d_ws;
    bf16* Wqkv_b = ws;                  // 3M (Wq|Wk|Wv stacked = [3072][1024]), then Wo
    bf16* Wo_b  = ws + 3 * M1;          // 1M
    bf16* W1_b  = ws + 4 * M1;          // 4M
    bf16* W2_b  = ws + 8 * M1;          // 4M
    bf16* qb    = ws + 12 * M1;         // 4M
    bf16* kb    = ws + 16 * M1;         // 4M
    bf16* vt    = ws + 20 * M1;         // 4M  V transposed [b,h,d,s]
    bf16* cx    = ws + 24 * M1;         // 4M  attention context
    bf16* h     = ws + 28 * M1;         // 4M  LN output (h1, then h2)
    bf16* ffb   = ws + 12 * M1;         // 16M, overlays qb/kb/vt/cx (dead by FF1)
    float* biasqkv = (float*)(ws + 24 * M1);  // 3072 floats in cx region (dead before attn writes cx)

    cvt4_kernel<<<dim3(4096), 256, 0, stream>>>(Wq, Wk, Wv, Wo, Wqkv_b);  // writes Wqkv_b + Wo_b
    cvt_kernel<<<dim3(4 * M1 / 1024), 256, 0, stream>>>(W1, W1_b, 4 * M1);
    cvt_kernel<<<dim3(4 * M1 / 1024), 256, 0, stream>>>(W2, W2_b, 4 * M1);
    concat_bias_kernel<<<dim3(12), 256, 0, stream>>>(bq, bk, bv, biasqkv);

    ln_kernel<<<dim3(TOKENS), 256, 0, stream>>>(x, g1, be1, h);
    gemm_qkv<<<dim3(64, 24), 256, 0, stream>>>(h, Wqkv_b, biasqkv, qb, kb, vt);
    attn_kernel<<<dim3(SEQ / 64, 32), 256, 0, stream>>>(qb, kb, vt, mask, cx);
    gemm_bt<2, float><<<dim3(64, 8), 256, 0, stream>>>(cx, Wo_b, bo, x, out, TOKENS, HIDDEN, HIDDEN);
    ln_kernel<<<dim3(TOKENS), 256, 0, stream>>>(out, g2, be2, h);
    gemm_bt<1, bf16><<<dim3(64, 32), 256, 0, stream>>>(h, W1_b, b1, nullptr, ffb, TOKENS, FFDIM, HIDDEN);
    gemm_bt<2, float><<<dim3(64, 8), 256, 0, stream>>>(ffb, W2_b, b2, out, out, TOKENS, HIDDEN, FFDIM);
}

// Round 7
// 392.837 us; speedup vs baseline: 1.0494x; 1.0494x over previous
//
#include <hip/hip_runtime.h>
#include <hip/hip_bf16.h>
#include <math.h>

typedef __bf16 bf16;
typedef __bf16 bf16x4v __attribute__((ext_vector_type(4)));
typedef __bf16 bf16x8 __attribute__((ext_vector_type(8)));
typedef float  f32x4  __attribute__((ext_vector_type(4)));

#define HIDDEN 1024
#define TOKENS 4096   // B*S = 2*2048
#define FFDIM  4096
#define SEQ    2048
#define NHEAD  16

#define LOG2E 1.44269504088896340736f

// async 16B global -> LDS (lane i lands at ldsbase + 16*i)
__device__ __forceinline__ void async_copy16(bf16* lds, const bf16* g)
{
    __builtin_amdgcn_global_load_lds(
        (__attribute__((address_space(1))) void*)g,
        (__attribute__((address_space(3))) void*)lds,
        16, 0, 0);
}

// ---------------- fp32 -> bf16 weight conversion ----------------
__global__ __launch_bounds__(256) void cvt_kernel(const float* __restrict__ in,
                                                  bf16* __restrict__ out, int n)
{
    int i = (blockIdx.x * 256 + threadIdx.x) * 4;
    if (i >= n) return;
    float4 v = *(const float4*)&in[i];
    bf16x4v o = { (bf16)v.x, (bf16)v.y, (bf16)v.z, (bf16)v.w };
    *(bf16x4v*)&out[i] = o;
}

// 4x 1M-element tensors -> contiguous bf16 (Wq|Wk|Wv|Wo)
__global__ __launch_bounds__(256) void cvt4_kernel(const float* __restrict__ s0,
    const float* __restrict__ s1, const float* __restrict__ s2, const float* __restrict__ s3,
    bf16* __restrict__ out)
{
    const int M1 = 1 << 20;
    int i = (blockIdx.x * 256 + threadIdx.x) * 4;
    int sel = i >> 20;
    const float* src = (sel == 0) ? s0 : (sel == 1) ? s1 : (sel == 2) ? s2 : s3;
    float4 v = *(const float4*)&src[i & (M1 - 1)];
    bf16x4v o = { (bf16)v.x, (bf16)v.y, (bf16)v.z, (bf16)v.w };
    *(bf16x4v*)&out[i] = o;
}

__global__ __launch_bounds__(256) void concat_bias_kernel(const float* __restrict__ bq,
    const float* __restrict__ bk, const float* __restrict__ bv, float* __restrict__ o)
{
    int i = blockIdx.x * 256 + threadIdx.x;   // 0..3071
    float v = (i < 1024) ? bq[i] : (i < 2048 ? bk[i - 1024] : bv[i - 2048]);
    o[i] = v;
}

// ---------------- LayerNorm: fp32 in -> bf16 out, one block per row ----------------
__global__ __launch_bounds__(256) void ln_kernel(const float* __restrict__ in,
    const float* __restrict__ g, const float* __restrict__ be, bf16* __restrict__ out)
{
    int row = blockIdx.x;
    int tid = threadIdx.x;
    const float* x = in + (size_t)row * HIDDEN;
    int i0 = tid * 4;
    float4 v = *(const float4*)&x[i0];
    float s  = v.x + v.y + v.z + v.w;
    float s2 = v.x*v.x + v.y*v.y + v.z*v.z + v.w*v.w;
    #pragma unroll
    for (int off = 32; off > 0; off >>= 1) { s += __shfl_xor(s, off); s2 += __shfl_xor(s2, off); }
    __shared__ float red[2][4];
    int wave = tid >> 6;
    if ((tid & 63) == 0) { red[0][wave] = s; red[1][wave] = s2; }
    __syncthreads();
    float ts  = red[0][0] + red[0][1] + red[0][2] + red[0][3];
    float ts2 = red[1][0] + red[1][1] + red[1][2] + red[1][3];
    float mu   = ts  * (1.0f / HIDDEN);
    float var  = ts2 * (1.0f / HIDDEN) - mu * mu;
    float rstd = rsqrtf(var + 1e-5f);
    float4 gg = *(const float4*)&g[i0];
    float4 bb = *(const float4*)&be[i0];
    bf16x4v o;
    o[0] = (bf16)((v.x - mu) * rstd * gg.x + bb.x);
    o[1] = (bf16)((v.y - mu) * rstd * gg.y + bb.y);
    o[2] = (bf16)((v.z - mu) * rstd * gg.z + bb.z);
    o[3] = (bf16)((v.w - mu) * rstd * gg.w + bb.w);
    *(bf16x4v*)&out[(size_t)row * HIDDEN + i0] = o;
}

// ---------------- generic GEMM: C[M,N] = A[M,K] @ Bt[N,K]^T + bias ----------------
// BK=64, XOR-swizzled LDS, single-buffer (r5 structure — measured best).
// EPI: 0 = bias, 1 = bias+GELU, 2 = bias+fp32 residual.
template<int BM, int EPI, typename OT>
__global__ __launch_bounds__(256) void gemm_bt(const bf16* __restrict__ A, const bf16* __restrict__ Bt,
    const float* __restrict__ bias, const float* __restrict__ res, OT* __restrict__ C,
    int M, int N, int K)
{
    constexpr int MT = BM / 32;                 // m-tiles per wave
    __shared__ bf16 As[BM * 64];
    __shared__ bf16 Bs[128 * 64];
    int tid  = threadIdx.x;
    int wave = tid >> 6, lane = tid & 63;
    int lm = lane & 15, quad = lane >> 4;
    int m0 = blockIdx.x * BM, n0 = blockIdx.y * 128;
    int wm = (wave >> 1) * (MT * 16), wn = (wave & 1) * 64;
    int r8 = lane >> 3, c8 = lane & 7;          // staging: 8 rows x 128B per copy
    int gsw = (c8 ^ (r8 & 7)) * 8;              // swizzled source column (elems)
    f32x4 acc[MT][4] = {};
    for (int k0 = 0; k0 < K; k0 += 64) {
        #pragma unroll
        for (int ch = wave; ch < BM / 8; ch += 4)
            async_copy16(As + ch * 512, &A[(size_t)(m0 + ch * 8 + r8) * K + k0 + gsw]);
        #pragma unroll
        for (int ch = wave; ch < 16; ch += 4)
            async_copy16(Bs + ch * 512, &Bt[(size_t)(n0 + ch * 8 + r8) * K + k0 + gsw]);
        __syncthreads();
        bf16x8 af[MT][2], bfr[4][2];
        #pragma unroll
        for (int ks = 0; ks < 2; ks++) {
            int co = ((ks * 4 + quad) ^ (lm & 7)) * 8;
            #pragma unroll
            for (int t = 0; t < MT; t++) af[t][ks]  = *(const bf16x8*)&As[(wm + t * 16 + lm) * 64 + co];
            #pragma unroll
            for (int t = 0; t < 4; t++)  bfr[t][ks] = *(const bf16x8*)&Bs[(wn + t * 16 + lm) * 64 + co];
        }
        #pragma unroll
        for (int mt = 0; mt < MT; mt++)
            #pragma unroll
            for (int nt = 0; nt < 4; nt++)
                #pragma unroll
                for (int ks = 0; ks < 2; ks++)
                    acc[mt][nt] = __builtin_amdgcn_mfma_f32_16x16x32_bf16(af[mt][ks], bfr[nt][ks], acc[mt][nt], 0, 0, 0);
        __syncthreads();
    }
    #pragma unroll
    for (int mt = 0; mt < MT; mt++) {
        #pragma unroll
        for (int nt = 0; nt < 4; nt++) {
            int col = n0 + wn + nt * 16 + lm;
            float bv = bias[col];
            #pragma unroll
            for (int r = 0; r < 4; r++) {
                int row = m0 + wm + mt * 16 + quad * 4 + r;
                float vv = acc[mt][nt][r] + bv;
                if (EPI == 1) vv = 0.5f * vv * (1.0f + erff(vv * 0.70710678118654752f));
                if (EPI == 2) vv += res[(size_t)row * N + col];
                C[(size_t)row * N + col] = (OT)vv;
            }
        }
    }
}

// ---------------- fused QKV GEMM: N=3072; V written transposed [b,h,d,s] ----------
__global__ __launch_bounds__(256) void gemm_qkv(const bf16* __restrict__ A, const bf16* __restrict__ W,
    const float* __restrict__ bias, bf16* __restrict__ qb, bf16* __restrict__ kb, bf16* __restrict__ vt)
{
    constexpr int K = HIDDEN;
    __shared__ bf16 As[128 * 64];
    __shared__ bf16 Bs[128 * 64];
    int tid  = threadIdx.x;
    int wave = tid >> 6, lane = tid & 63;
    int lm = lane & 15, quad = lane >> 4;
    int m0 = blockIdx.x * 128, n0 = blockIdx.y * 128;
    int wm = (wave >> 1) * 64, wn = (wave & 1) * 64;
    int r8 = lane >> 3, c8 = lane & 7;
    int gsw = (c8 ^ (r8 & 7)) * 8;
    f32x4 acc[4][4] = {};
    for (int k0 = 0; k0 < K; k0 += 64) {
        #pragma unroll
        for (int ch = wave; ch < 16; ch += 4) {
            async_copy16(As + ch * 512, &A[(size_t)(m0 + ch * 8 + r8) * K + k0 + gsw]);
            async_copy16(Bs + ch * 512, &W[(size_t)(n0 + ch * 8 + r8) * K + k0 + gsw]);
        }
        __syncthreads();
        bf16x8 af[4][2], bfr[4][2];
        #pragma unroll
        for (int ks = 0; ks < 2; ks++) {
            int co = ((ks * 4 + quad) ^ (lm & 7)) * 8;
            #pragma unroll
            for (int t = 0; t < 4; t++) {
                af[t][ks]  = *(const bf16x8*)&As[(wm + t * 16 + lm) * 64 + co];
                bfr[t][ks] = *(const bf16x8*)&Bs[(wn + t * 16 + lm) * 64 + co];
            }
        }
        #pragma unroll
        for (int mt = 0; mt < 4; mt++)
            #pragma unroll
            for (int nt = 0; nt < 4; nt++)
                #pragma unroll
                for (int ks = 0; ks < 2; ks++)
                    acc[mt][nt] = __builtin_amdgcn_mfma_f32_16x16x32_bf16(af[mt][ks], bfr[nt][ks], acc[mt][nt], 0, 0, 0);
        __syncthreads();
    }
    int region = n0 >> 10;    // 0:Q 1:K 2:V  (block-uniform; 1024 % 128 == 0)
    #pragma unroll
    for (int mt = 0; mt < 4; mt++) {
        #pragma unroll
        for (int nt = 0; nt < 4; nt++) {
            int col = n0 + wn + nt * 16 + lm;
            float bv = bias[col];
            int cl = col & 1023;
            #pragma unroll
            for (int r = 0; r < 4; r++) {
                int row = m0 + wm + mt * 16 + quad * 4 + r;
                float vv = acc[mt][nt][r] + bv;
                if (region == 0)      qb[(size_t)row * HIDDEN + cl] = (bf16)vv;
                else if (region == 1) kb[(size_t)row * HIDDEN + cl] = (bf16)vv;
                else {
                    int h = cl >> 6, d = cl & 63;
                    int b = row >> 11, s = row & 2047;
                    vt[(((size_t)(b * NHEAD + h)) * 64 + d) * SEQ + s] = (bf16)vv;
                }
            }
        }
    }
}

// ---------------- Flash attention: 512 threads, 8 waves, 128 q-rows per block -----
// Single-buffer K/V staging (occupancy), fixed-shift softmax, MFMA row-sums.
__global__ __launch_bounds__(512) void attn_kernel(const bf16* __restrict__ Q, const bf16* __restrict__ K,
    const bf16* __restrict__ Vt, const float* __restrict__ mask, bf16* __restrict__ O)
{
    __shared__ bf16 Ks[64 * 64];        // [krow][d], 16B-chunk swizzled
    __shared__ bf16 Vs[64 * 64];        // [d][s],    16B-chunk swizzled
    __shared__ bf16 Ps[8][16 * 72];     // per-wave P [q][k], row stride 72
    int tid = threadIdx.x, wave = tid >> 6, lane = tid & 63;
    int lm = lane & 15, quad = lane >> 4;
    int bh = blockIdx.y, b = bh >> 4, h = bh & 15;
    int q0 = blockIdx.x * 128 + wave * 16;
    const size_t base  = ((size_t)b * SEQ) * HIDDEN + h * 64;   // Q/K token-major
    const size_t vbase = (size_t)bh * 64 * SEQ;                 // Vt [bh][d][s]
    int srow8 = lane >> 3, spos = lane & 7;
    bf16x8 qf[2];
    #pragma unroll
    for (int ks = 0; ks < 2; ks++)
        qf[ks] = *(const bf16x8*)&Q[base + (size_t)(q0 + lm) * HIDDEN + ks * 32 + quad * 8];
    bf16x8 onesf;
    #pragma unroll
    for (int i = 0; i < 8; i++) onesf[i] = (bf16)1.0f;
    f32x4 o[4] = {};
    f32x4 lacc = {};                               // row-sums via MFMA vs ones
    const float c0 = 0.125f * LOG2E;               // score scale, log2 domain
    const float cmk = 10000.0f * LOG2E;            // mask scale, log2 domain
    const float coff = -(cmk + 16.0f);             // folds (mv-1)*cmk - SHIFT
    bf16* pw = &Ps[wave][0];
    for (int kt = 0; kt < SEQ; kt += 64) {
        __syncthreads();   // prior tile's reads of Ks/Vs done
        {
            // 8 waves, each stages exactly one 8-row chunk of Ks and of Vs
            int r = wave * 8 + srow8;
            int gc = spos ^ (r & 7);
            async_copy16(&Ks[wave * 512], &K [base  + (size_t)(kt + r) * HIDDEN + gc * 8]);
            async_copy16(&Vs[wave * 512], &Vt[vbase + (size_t)r * SEQ + kt + gc * 8]);
        }
        __syncthreads();   // staged data visible
        // S^T: rows = k (reg dim), cols = q (lm)
        f32x4 st[4] = {};
        #pragma unroll
        for (int nt = 0; nt < 4; nt++) {
            #pragma unroll
            for (int ks = 0; ks < 2; ks++) {
                bf16x8 kf = *(const bf16x8*)&Ks[(nt * 16 + lm) * 64 + (((ks * 4 + quad) ^ (lm & 7)) * 8)];
                st[nt] = __builtin_amdgcn_mfma_f32_16x16x32_bf16(kf, qf[ks], st[nt], 0, 0, 0);
            }
        }
        // p = exp2(s*c0 + mv*cmk + coff); pack straight to P (per-wave LDS region)
        #pragma unroll
        for (int nt = 0; nt < 4; nt++) {
            float4 mv = *(const float4*)&mask[b * SEQ + kt + nt * 16 + quad * 4];
            float p0 = __builtin_amdgcn_exp2f(st[nt][0] * c0 + (mv.x * cmk + coff));
            float p1 = __builtin_amdgcn_exp2f(st[nt][1] * c0 + (mv.y * cmk + coff));
            float p2 = __builtin_amdgcn_exp2f(st[nt][2] * c0 + (mv.z * cmk + coff));
            float p3 = __builtin_amdgcn_exp2f(st[nt][3] * c0 + (mv.w * cmk + coff));
            bf16x4v pk = { (bf16)p0, (bf16)p1, (bf16)p2, (bf16)p3 };
            *(bf16x4v*)&pw[lm * 72 + nt * 16 + quad * 4] = pk;
        }
        // O += P @ V ; lacc += P @ ones (row-sums, already in C-layout for epilogue)
        bf16x8 pf[2];
        #pragma unroll
        for (int ks = 0; ks < 2; ks++)
            pf[ks] = *(const bf16x8*)&pw[lm * 72 + ks * 32 + quad * 8];
        lacc = __builtin_amdgcn_mfma_f32_16x16x32_bf16(pf[0], onesf, lacc, 0, 0, 0);
        lacc = __builtin_amdgcn_mfma_f32_16x16x32_bf16(pf[1], onesf, lacc, 0, 0, 0);
        #pragma unroll
        for (int dt = 0; dt < 4; dt++) {
            #pragma unroll
            for (int ks = 0; ks < 2; ks++) {
                bf16x8 vf = *(const bf16x8*)&Vs[(dt * 16 + lm) * 64 + (((ks * 4 + quad) ^ (lm & 7)) * 8)];
                o[dt] = __builtin_amdgcn_mfma_f32_16x16x32_bf16(pf[ks], vf, o[dt], 0, 0, 0);
            }
        }
    }
    #pragma unroll
    for (int r = 0; r < 4; r++) {
        float inv = 1.0f / lacc[r];                // sum for q-row quad*4+r (all cols equal)
        #pragma unroll
        for (int dt = 0; dt < 4; dt++) {
            float val = o[dt][r] * inv;
            O[base + (size_t)(q0 + quad * 4 + r) * HIDDEN + dt * 16 + lm] = (bf16)val;
        }
    }
}

extern "C" void kernel_launch(void* const* d_in, const int* in_sizes, int n_in,
                              void* d_out, int out_size, void* d_ws, size_t ws_size,
                              hipStream_t stream)
{
    (void)in_sizes; (void)n_in; (void)out_size; (void)ws_size;
    const float* x    = (const float*)d_in[0];
    const float* mask = (const float*)d_in[1];
    const float* Wq   = (const float*)d_in[2];
    const float* bq   = (const float*)d_in[3];
    const float* Wk   = (const float*)d_in[4];
    const float* bk   = (const float*)d_in[5];
    const float* Wv   = (const float*)d_in[6];
    const float* bv   = (const float*)d_in[7];
    const float* Wo   = (const float*)d_in[8];
    const float* bo   = (const float*)d_in[9];
    const float* W1   = (const float*)d_in[10];
    const float* b1   = (const float*)d_in[11];
    const float* W2   = (const float*)d_in[12];
    const float* b2   = (const float*)d_in[13];
    const float* g1   = (const float*)d_in[14];
    const float* be1  = (const float*)d_in[15];
    const float* g2   = (const float*)d_in[16];
    const float* be2  = (const float*)d_in[17];
    float* out = (float*)d_out;

    const size_t M1 = 1024u * 1024u;
    bf16* ws    = (bf16*)d_ws;
    bf16* Wqkv_b = ws;                  // 3M (Wq|Wk|Wv stacked = [3072][1024]), then Wo
    bf16* Wo_b  = ws + 3 * M1;          // 1M
    bf16* W1_b  = ws + 4 * M1;          // 4M
    bf16* W2_b  = ws + 8 * M1;          // 4M
    bf16* qb    = ws + 12 * M1;         // 4M
    bf16* kb    = ws + 16 * M1;         // 4M
    bf16* vt    = ws + 20 * M1;         // 4M  V transposed [b,h,d,s]
    bf16* cx    = ws + 24 * M1;         // 4M  attention context
    bf16* h     = ws + 28 * M1;         // 4M  LN output (h1, then h2)
    bf16* ffb   = ws + 12 * M1;         // 16M, overlays qb/kb/vt/cx (dead by FF1)
    float* biasqkv = (float*)(ws + 24 * M1);  // 3072 floats in cx region (dead before attn writes cx)

    cvt4_kernel<<<dim3(4096), 256, 0, stream>>>(Wq, Wk, Wv, Wo, Wqkv_b);  // writes Wqkv_b + Wo_b
    cvt_kernel<<<dim3(4 * M1 / 1024), 256, 0, stream>>>(W1, W1_b, 4 * M1);
    cvt_kernel<<<dim3(4 * M1 / 1024), 256, 0, stream>>>(W2, W2_b, 4 * M1);
    concat_bias_kernel<<<dim3(12), 256, 0, stream>>>(bq, bk, bv, biasqkv);

    ln_kernel<<<dim3(TOKENS), 256, 0, stream>>>(x, g1, be1, h);
    gemm_qkv<<<dim3(32, 24), 256, 0, stream>>>(h, Wqkv_b, biasqkv, qb, kb, vt);
    attn_kernel<<<dim3(SEQ / 128, 32), 512, 0, stream>>>(qb, kb, vt, mask, cx);
    gemm_bt<64, 2, float><<<dim3(64, 8), 256, 0, stream>>>(cx, Wo_b, bo, x, out, TOKENS, HIDDEN, HIDDEN);
    ln_kernel<<<dim3(TOKENS), 256, 0, stream>>>(out, g2, be2, h);
    gemm_bt<128, 1, bf16><<<dim3(32, 32), 256, 0, stream>>>(h, W1_b, b1, nullptr, ffb, TOKENS, FFDIM, HIDDEN);
    gemm_bt<64, 2, float><<<dim3(64, 8), 256, 0, stream>>>(ffb, W2_b, b2, out, out, TOKENS, HIDDEN, FFDIM);
}

// Round 8
// 384.482 us; speedup vs baseline: 1.0722x; 1.0217x over previous
//
#include <hip/hip_runtime.h>
#include <hip/hip_bf16.h>
#include <math.h>

typedef __bf16 bf16;
typedef __bf16 bf16x4v __attribute__((ext_vector_type(4)));
typedef __bf16 bf16x8 __attribute__((ext_vector_type(8)));
typedef float  f32x4  __attribute__((ext_vector_type(4)));

#define HIDDEN 1024
#define TOKENS 4096   // B*S = 2*2048
#define FFDIM  4096
#define SEQ    2048
#define NHEAD  16

#define LOG2E 1.44269504088896340736f

// async 16B global -> LDS (lane i lands at ldsbase + 16*i)
__device__ __forceinline__ void async_copy16(bf16* lds, const bf16* g)
{
    __builtin_amdgcn_global_load_lds(
        (__attribute__((address_space(1))) void*)g,
        (__attribute__((address_space(3))) void*)lds,
        16, 0, 0);
}

// ---------------- all weights fp32 -> bf16, one launch ----------------
// Output layout: Wq|Wk|Wv|Wo|W1|W2 contiguous (1M,1M,1M,1M,4M,4M elems)
__global__ __launch_bounds__(256) void cvt_all_kernel(const float* __restrict__ wq,
    const float* __restrict__ wk, const float* __restrict__ wv, const float* __restrict__ wo,
    const float* __restrict__ w1, const float* __restrict__ w2, bf16* __restrict__ out)
{
    size_t i = ((size_t)blockIdx.x * 256 + threadIdx.x) * 4;
    int sel = (int)(i >> 20);
    const float* src;
    size_t off;
    if (sel < 4) { src = (sel == 0) ? wq : (sel == 1) ? wk : (sel == 2) ? wv : wo; off = i & ((1u << 20) - 1); }
    else if (sel < 8) { src = w1; off = i - ((size_t)4 << 20); }
    else              { src = w2; off = i - ((size_t)8 << 20); }
    float4 v = *(const float4*)&src[off];
    bf16x4v o = { (bf16)v.x, (bf16)v.y, (bf16)v.z, (bf16)v.w };
    *(bf16x4v*)&out[i] = o;
}

__global__ __launch_bounds__(256) void concat_bias_kernel(const float* __restrict__ bq,
    const float* __restrict__ bk, const float* __restrict__ bv, float* __restrict__ o)
{
    int i = blockIdx.x * 256 + threadIdx.x;   // 0..3071
    float v = (i < 1024) ? bq[i] : (i < 2048 ? bk[i - 1024] : bv[i - 2048]);
    o[i] = v;
}

// ---------------- LayerNorm: fp32 in -> bf16 out, one block per row ----------------
__global__ __launch_bounds__(256) void ln_kernel(const float* __restrict__ in,
    const float* __restrict__ g, const float* __restrict__ be, bf16* __restrict__ out)
{
    int row = blockIdx.x;
    int tid = threadIdx.x;
    const float* x = in + (size_t)row * HIDDEN;
    int i0 = tid * 4;
    float4 v = *(const float4*)&x[i0];
    float s  = v.x + v.y + v.z + v.w;
    float s2 = v.x*v.x + v.y*v.y + v.z*v.z + v.w*v.w;
    #pragma unroll
    for (int off = 32; off > 0; off >>= 1) { s += __shfl_xor(s, off); s2 += __shfl_xor(s2, off); }
    __shared__ float red[2][4];
    int wave = tid >> 6;
    if ((tid & 63) == 0) { red[0][wave] = s; red[1][wave] = s2; }
    __syncthreads();
    float ts  = red[0][0] + red[0][1] + red[0][2] + red[0][3];
    float ts2 = red[1][0] + red[1][1] + red[1][2] + red[1][3];
    float mu   = ts  * (1.0f / HIDDEN);
    float var  = ts2 * (1.0f / HIDDEN) - mu * mu;
    float rstd = rsqrtf(var + 1e-5f);
    float4 gg = *(const float4*)&g[i0];
    float4 bb = *(const float4*)&be[i0];
    bf16x4v o;
    o[0] = (bf16)((v.x - mu) * rstd * gg.x + bb.x);
    o[1] = (bf16)((v.y - mu) * rstd * gg.y + bb.y);
    o[2] = (bf16)((v.z - mu) * rstd * gg.z + bb.z);
    o[3] = (bf16)((v.w - mu) * rstd * gg.w + bb.w);
    *(bf16x4v*)&out[(size_t)row * HIDDEN + i0] = o;
}

// ---------------- generic GEMM: C[M,N] = A[M,K] @ Bt[N,K]^T + bias ----------------
// BK=64, XOR-swizzled LDS, single-buffer (r5 structure — measured best).
// EPI: 0 = bias, 1 = bias+GELU, 2 = bias+fp32 residual.
template<int BM, int EPI, typename OT>
__global__ __launch_bounds__(256) void gemm_bt(const bf16* __restrict__ A, const bf16* __restrict__ Bt,
    const float* __restrict__ bias, const float* __restrict__ res, OT* __restrict__ C,
    int M, int N, int K)
{
    constexpr int MT = BM / 32;                 // m-tiles per wave
    __shared__ bf16 As[BM * 64];
    __shared__ bf16 Bs[128 * 64];
    int tid  = threadIdx.x;
    int wave = tid >> 6, lane = tid & 63;
    int lm = lane & 15, quad = lane >> 4;
    int m0 = blockIdx.x * BM, n0 = blockIdx.y * 128;
    int wm = (wave >> 1) * (MT * 16), wn = (wave & 1) * 64;
    int r8 = lane >> 3, c8 = lane & 7;          // staging: 8 rows x 128B per copy
    int gsw = (c8 ^ (r8 & 7)) * 8;              // swizzled source column (elems)
    f32x4 acc[MT][4] = {};
    for (int k0 = 0; k0 < K; k0 += 64) {
        #pragma unroll
        for (int ch = wave; ch < BM / 8; ch += 4)
            async_copy16(As + ch * 512, &A[(size_t)(m0 + ch * 8 + r8) * K + k0 + gsw]);
        #pragma unroll
        for (int ch = wave; ch < 16; ch += 4)
            async_copy16(Bs + ch * 512, &Bt[(size_t)(n0 + ch * 8 + r8) * K + k0 + gsw]);
        __syncthreads();
        bf16x8 af[MT][2], bfr[4][2];
        #pragma unroll
        for (int ks = 0; ks < 2; ks++) {
            int co = ((ks * 4 + quad) ^ (lm & 7)) * 8;
            #pragma unroll
            for (int t = 0; t < MT; t++) af[t][ks]  = *(const bf16x8*)&As[(wm + t * 16 + lm) * 64 + co];
            #pragma unroll
            for (int t = 0; t < 4; t++)  bfr[t][ks] = *(const bf16x8*)&Bs[(wn + t * 16 + lm) * 64 + co];
        }
        #pragma unroll
        for (int mt = 0; mt < MT; mt++)
            #pragma unroll
            for (int nt = 0; nt < 4; nt++)
                #pragma unroll
                for (int ks = 0; ks < 2; ks++)
                    acc[mt][nt] = __builtin_amdgcn_mfma_f32_16x16x32_bf16(af[mt][ks], bfr[nt][ks], acc[mt][nt], 0, 0, 0);
        __syncthreads();
    }
    #pragma unroll
    for (int mt = 0; mt < MT; mt++) {
        #pragma unroll
        for (int nt = 0; nt < 4; nt++) {
            int col = n0 + wn + nt * 16 + lm;
            float bv = bias[col];
            #pragma unroll
            for (int r = 0; r < 4; r++) {
                int row = m0 + wm + mt * 16 + quad * 4 + r;
                float vv = acc[mt][nt][r] + bv;
                if (EPI == 1) vv = 0.5f * vv * (1.0f + erff(vv * 0.70710678118654752f));
                if (EPI == 2) vv += res[(size_t)row * N + col];
                C[(size_t)row * N + col] = (OT)vv;
            }
        }
    }
}

// ---------------- fused QKV GEMM: N=3072; V written transposed [b,h,d,s] ----------
__global__ __launch_bounds__(256) void gemm_qkv(const bf16* __restrict__ A, const bf16* __restrict__ W,
    const float* __restrict__ bias, bf16* __restrict__ qb, bf16* __restrict__ kb, bf16* __restrict__ vt)
{
    constexpr int K = HIDDEN;
    __shared__ bf16 As[128 * 64];
    __shared__ bf16 Bs[128 * 64];
    int tid  = threadIdx.x;
    int wave = tid >> 6, lane = tid & 63;
    int lm = lane & 15, quad = lane >> 4;
    int m0 = blockIdx.x * 128, n0 = blockIdx.y * 128;
    int wm = (wave >> 1) * 64, wn = (wave & 1) * 64;
    int r8 = lane >> 3, c8 = lane & 7;
    int gsw = (c8 ^ (r8 & 7)) * 8;
    f32x4 acc[4][4] = {};
    for (int k0 = 0; k0 < K; k0 += 64) {
        #pragma unroll
        for (int ch = wave; ch < 16; ch += 4) {
            async_copy16(As + ch * 512, &A[(size_t)(m0 + ch * 8 + r8) * K + k0 + gsw]);
            async_copy16(Bs + ch * 512, &W[(size_t)(n0 + ch * 8 + r8) * K + k0 + gsw]);
        }
        __syncthreads();
        bf16x8 af[4][2], bfr[4][2];
        #pragma unroll
        for (int ks = 0; ks < 2; ks++) {
            int co = ((ks * 4 + quad) ^ (lm & 7)) * 8;
            #pragma unroll
            for (int t = 0; t < 4; t++) {
                af[t][ks]  = *(const bf16x8*)&As[(wm + t * 16 + lm) * 64 + co];
                bfr[t][ks] = *(const bf16x8*)&Bs[(wn + t * 16 + lm) * 64 + co];
            }
        }
        #pragma unroll
        for (int mt = 0; mt < 4; mt++)
            #pragma unroll
            for (int nt = 0; nt < 4; nt++)
                #pragma unroll
                for (int ks = 0; ks < 2; ks++)
                    acc[mt][nt] = __builtin_amdgcn_mfma_f32_16x16x32_bf16(af[mt][ks], bfr[nt][ks], acc[mt][nt], 0, 0, 0);
        __syncthreads();
    }
    int region = n0 >> 10;    // 0:Q 1:K 2:V  (block-uniform; 1024 % 128 == 0)
    #pragma unroll
    for (int mt = 0; mt < 4; mt++) {
        #pragma unroll
        for (int nt = 0; nt < 4; nt++) {
            int col = n0 + wn + nt * 16 + lm;
            float bv = bias[col];
            int cl = col & 1023;
            #pragma unroll
            for (int r = 0; r < 4; r++) {
                int row = m0 + wm + mt * 16 + quad * 4 + r;
                float vv = acc[mt][nt][r] + bv;
                if (region == 0)      qb[(size_t)row * HIDDEN + cl] = (bf16)vv;
                else if (region == 1) kb[(size_t)row * HIDDEN + cl] = (bf16)vv;
                else {
                    int h = cl >> 6, d = cl & 63;
                    int b = row >> 11, s = row & 2047;
                    vt[(((size_t)(b * NHEAD + h)) * 64 + d) * SEQ + s] = (bf16)vv;
                }
            }
        }
    }
}

// ---------------- Flash attention: 512 thr / 8 waves / 128 q-rows, KV dbuf --------
// Double-buffered K/V staging: one barrier per tile; copies for tile t+1 issued
// right after the barrier for tile t -> a full tile of compute hides them.
// LDS 50.4 KB -> 3 blocks/CU by LDS, grid 512 -> 2/CU (same co-residency as r7).
__global__ __launch_bounds__(512) void attn_kernel(const bf16* __restrict__ Q, const bf16* __restrict__ K,
    const bf16* __restrict__ Vt, const float* __restrict__ mask, bf16* __restrict__ O)
{
    __shared__ bf16 Ks[2][64 * 64];     // [krow][d], 16B-chunk swizzled
    __shared__ bf16 Vs[2][64 * 64];     // [d][s],    16B-chunk swizzled
    __shared__ bf16 Ps[8][16 * 72];     // per-wave P [q][k], row stride 72
    int tid = threadIdx.x, wave = tid >> 6, lane = tid & 63;
    int lm = lane & 15, quad = lane >> 4;
    int bh = blockIdx.y, b = bh >> 4, h = bh & 15;
    int q0 = blockIdx.x * 128 + wave * 16;
    const size_t base  = ((size_t)b * SEQ) * HIDDEN + h * 64;   // Q/K token-major
    const size_t vbase = (size_t)bh * 64 * SEQ;                 // Vt [bh][d][s]
    int srow8 = lane >> 3, spos = lane & 7;
    bf16x8 qf[2];
    #pragma unroll
    for (int ks = 0; ks < 2; ks++)
        qf[ks] = *(const bf16x8*)&Q[base + (size_t)(q0 + lm) * HIDDEN + ks * 32 + quad * 8];
    bf16x8 onesf;
    #pragma unroll
    for (int i = 0; i < 8; i++) onesf[i] = (bf16)1.0f;
    f32x4 o[4] = {};
    f32x4 lacc = {};                               // row-sums via MFMA vs ones
    const float c0 = 0.125f * LOG2E;               // score scale, log2 domain
    const float cmk = 10000.0f * LOG2E;            // mask scale, log2 domain
    const float coff = -(cmk + 16.0f);             // folds (mv-1)*cmk - SHIFT
    bf16* pw = &Ps[wave][0];
    int r = wave * 8 + srow8;                      // this wave's staging row
    int gc = spos ^ (r & 7);                       // swizzled source chunk
    auto stage = [&](int buf, int kt) {
        async_copy16(&Ks[buf][wave * 512], &K [base  + (size_t)(kt + r) * HIDDEN + gc * 8]);
        async_copy16(&Vs[buf][wave * 512], &Vt[vbase + (size_t)r * SEQ + kt + gc * 8]);
    };
    stage(0, 0);
    for (int ti = 0; ti < SEQ / 64; ti++) {
        __syncthreads();                           // buf[ti&1] visible; buf[(ti+1)&1] readers done
        if (ti + 1 < SEQ / 64) stage((ti + 1) & 1, (ti + 1) * 64);
        const bf16* ksb = Ks[ti & 1];
        const bf16* vsb = Vs[ti & 1];
        int kt = ti * 64;
        // S^T: rows = k (reg dim), cols = q (lm)
        f32x4 st[4] = {};
        #pragma unroll
        for (int nt = 0; nt < 4; nt++) {
            #pragma unroll
            for (int ks = 0; ks < 2; ks++) {
                bf16x8 kf = *(const bf16x8*)&ksb[(nt * 16 + lm) * 64 + (((ks * 4 + quad) ^ (lm & 7)) * 8)];
                st[nt] = __builtin_amdgcn_mfma_f32_16x16x32_bf16(kf, qf[ks], st[nt], 0, 0, 0);
            }
        }
        // p = exp2(s*c0 + mv*cmk + coff); pack straight to P (per-wave LDS region)
        #pragma unroll
        for (int nt = 0; nt < 4; nt++) {
            float4 mv = *(const float4*)&mask[b * SEQ + kt + nt * 16 + quad * 4];
            float p0 = __builtin_amdgcn_exp2f(st[nt][0] * c0 + (mv.x * cmk + coff));
            float p1 = __builtin_amdgcn_exp2f(st[nt][1] * c0 + (mv.y * cmk + coff));
            float p2 = __builtin_amdgcn_exp2f(st[nt][2] * c0 + (mv.z * cmk + coff));
            float p3 = __builtin_amdgcn_exp2f(st[nt][3] * c0 + (mv.w * cmk + coff));
            bf16x4v pk = { (bf16)p0, (bf16)p1, (bf16)p2, (bf16)p3 };
            *(bf16x4v*)&pw[lm * 72 + nt * 16 + quad * 4] = pk;
        }
        // O += P @ V ; lacc += P @ ones (row-sums, already in C-layout for epilogue)
        bf16x8 pf[2];
        #pragma unroll
        for (int ks = 0; ks < 2; ks++)
            pf[ks] = *(const bf16x8*)&pw[lm * 72 + ks * 32 + quad * 8];
        lacc = __builtin_amdgcn_mfma_f32_16x16x32_bf16(pf[0], onesf, lacc, 0, 0, 0);
        lacc = __builtin_amdgcn_mfma_f32_16x16x32_bf16(pf[1], onesf, lacc, 0, 0, 0);
        #pragma unroll
        for (int dt = 0; dt < 4; dt++) {
            #pragma unroll
            for (int ks = 0; ks < 2; ks++) {
                bf16x8 vf = *(const bf16x8*)&vsb[(dt * 16 + lm) * 64 + (((ks * 4 + quad) ^ (lm & 7)) * 8)];
                o[dt] = __builtin_amdgcn_mfma_f32_16x16x32_bf16(pf[ks], vf, o[dt], 0, 0, 0);
            }
        }
    }
    #pragma unroll
    for (int rr = 0; rr < 4; rr++) {
        float inv = 1.0f / lacc[rr];               // sum for q-row quad*4+rr (all cols equal)
        #pragma unroll
        for (int dt = 0; dt < 4; dt++) {
            float val = o[dt][rr] * inv;
            O[base + (size_t)(q0 + quad * 4 + rr) * HIDDEN + dt * 16 + lm] = (bf16)val;
        }
    }
}

extern "C" void kernel_launch(void* const* d_in, const int* in_sizes, int n_in,
                              void* d_out, int out_size, void* d_ws, size_t ws_size,
                              hipStream_t stream)
{
    (void)in_sizes; (void)n_in; (void)out_size; (void)ws_size;
    const float* x    = (const float*)d_in[0];
    const float* mask = (const float*)d_in[1];
    const float* Wq   = (const float*)d_in[2];
    const float* bq   = (const float*)d_in[3];
    const float* Wk   = (const float*)d_in[4];
    const float* bk   = (const float*)d_in[5];
    const float* Wv   = (const float*)d_in[6];
    const float* bv   = (const float*)d_in[7];
    const float* Wo   = (const float*)d_in[8];
    const float* bo   = (const float*)d_in[9];
    const float* W1   = (const float*)d_in[10];
    const float* b1   = (const float*)d_in[11];
    const float* W2   = (const float*)d_in[12];
    const float* b2   = (const float*)d_in[13];
    const float* g1   = (const float*)d_in[14];
    const float* be1  = (const float*)d_in[15];
    const float* g2   = (const float*)d_in[16];
    const float* be2  = (const float*)d_in[17];
    float* out = (float*)d_out;

    const size_t M1 = 1024u * 1024u;
    bf16* ws    = (bf16*)d_ws;
    bf16* Wqkv_b = ws;                  // 3M (Wq|Wk|Wv stacked = [3072][1024]), then Wo
    bf16* Wo_b  = ws + 3 * M1;          // 1M
    bf16* W1_b  = ws + 4 * M1;          // 4M
    bf16* W2_b  = ws + 8 * M1;          // 4M
    bf16* qb    = ws + 12 * M1;         // 4M
    bf16* kb    = ws + 16 * M1;         // 4M
    bf16* vt    = ws + 20 * M1;         // 4M  V transposed [b,h,d,s]
    bf16* cx    = ws + 24 * M1;         // 4M  attention context
    bf16* h     = ws + 28 * M1;         // 4M  LN output (h1, then h2)
    bf16* ffb   = ws + 12 * M1;         // 16M, overlays qb/kb/vt/cx (dead by FF1)
    float* biasqkv = (float*)(ws + 24 * M1);  // 3072 floats in cx region (dead before attn writes cx)

    cvt_all_kernel<<<dim3(12288), 256, 0, stream>>>(Wq, Wk, Wv, Wo, W1, W2, Wqkv_b);
    concat_bias_kernel<<<dim3(12), 256, 0, stream>>>(bq, bk, bv, biasqkv);

    ln_kernel<<<dim3(TOKENS), 256, 0, stream>>>(x, g1, be1, h);
    gemm_qkv<<<dim3(32, 24), 256, 0, stream>>>(h, Wqkv_b, biasqkv, qb, kb, vt);
    attn_kernel<<<dim3(SEQ / 128, 32), 512, 0, stream>>>(qb, kb, vt, mask, cx);
    gemm_bt<64, 2, float><<<dim3(64, 8), 256, 0, stream>>>(cx, Wo_b, bo, x, out, TOKENS, HIDDEN, HIDDEN);
    ln_kernel<<<dim3(TOKENS), 256, 0, stream>>>(out, g2, be2, h);
    gemm_bt<128, 1, bf16><<<dim3(32, 32), 256, 0, stream>>>(h, W1_b, b1, nullptr, ffb, TOKENS, FFDIM, HIDDEN);
    gemm_bt<64, 2, float><<<dim3(64, 8), 256, 0, stream>>>(ffb, W2_b, b2, out, out, TOKENS, HIDDEN, FFDIM);
}